// Round 9
// baseline (229.621 us; speedup 1.0000x reference)
//
#include <hip/hip_runtime.h>

#define T_SEQ 2048
#define DIM   2048
#define NH    16
#define HD    128
#define KVR   512

typedef unsigned short ushort_t;
typedef __attribute__((ext_vector_type(8)))  short   short8;
typedef __attribute__((ext_vector_type(8)))  __bf16  bf16x8;
typedef __attribute__((ext_vector_type(4)))  float   f32x4;
typedef __attribute__((ext_vector_type(16))) float   f32x16;
typedef __attribute__((ext_vector_type(4)))  unsigned int u32x4;
typedef __attribute__((ext_vector_type(2)))  unsigned int u32x2;

union V8 { short8 s; bf16x8 b; u32x4 u; };

__device__ inline float b2f(ushort_t u) {
    union { unsigned u; float f; } x; x.u = ((unsigned)u) << 16; return x.f;
}
__device__ inline ushort_t f2b(float f) {
    union { float f; unsigned u; } x; x.f = f;
    unsigned r = x.u + 0x7FFFu + ((x.u >> 16) & 1u);
    return (ushort_t)(r >> 16);
}
__device__ inline unsigned pk2(float a, float b) {
    return (unsigned)f2b(a) | ((unsigned)f2b(b) << 16);
}

__device__ __forceinline__ void gld16(char* lds, const ushort_t* g) {
    __builtin_amdgcn_global_load_lds(
        (const __attribute__((address_space(1))) unsigned int*)g,
        (__attribute__((address_space(3))) unsigned int*)lds,
        16, 0, 0);
}

// ---------------------------------------------------------------------------
// Batched f32 -> bf16 conversion (unchanged).
// ---------------------------------------------------------------------------
__global__ __launch_bounds__(256) void cvtk(
    const float* __restrict__ a0, const float* __restrict__ a1,
    const float* __restrict__ a2, const float* __restrict__ a3,
    const float* __restrict__ a4,
    ushort_t* __restrict__ b0, ushort_t* __restrict__ b1,
    ushort_t* __restrict__ b2, ushort_t* __restrict__ b3,
    ushort_t* __restrict__ b4)
{
    const int N0 = 524288, N1 = 1048576, N2 = 1179648, N3 = 1441792, N4 = 1966080;
    for (int c = blockIdx.x * blockDim.x + threadIdx.x; c < N4; c += gridDim.x * blockDim.x) {
        const float* s; ushort_t* d; int off;
        if      (c < N0) { s = a0; d = b0; off = c; }
        else if (c < N1) { s = a1; d = b1; off = c - N0; }
        else if (c < N2) { s = a2; d = b2; off = c - N1; }
        else if (c < N3) { s = a3; d = b3; off = c - N2; }
        else             { s = a4; d = b4; off = c - N3; }
        f32x4 lo = *(const f32x4*)(s + (size_t)off * 8);
        f32x4 hi = *(const f32x4*)(s + (size_t)off * 8 + 4);
        V8 v;
        #pragma unroll
        for (int e = 0; e < 4; ++e) { v.b[e] = (__bf16)lo[e]; v.b[e + 4] = (__bf16)hi[e]; }
        *(u32x4*)(d + (size_t)off * 8) = v.u;
    }
}

// ---------------------------------------------------------------------------
// NT GEMM, all-bf16 inputs (unchanged).
// ---------------------------------------------------------------------------
template <bool OUT_F32>
__global__ __launch_bounds__(256, 2) void gemm_nt(
    const ushort_t* __restrict__ A, const ushort_t* __restrict__ B,
    void* __restrict__ Cv, int M, int K,
    const ushort_t* __restrict__ B2, void* __restrict__ C2, int Nsplit, int N2)
{
    __shared__ __align__(16) char sA[2][16384];
    __shared__ __align__(16) char sB[2][16384];

    const int tid  = threadIdx.x;
    const int wave = tid >> 6;
    const int lane = tid & 63;
    const int l15  = lane & 15;
    const int l4   = lane >> 4;
    const int bm   = blockIdx.x * 128;
    const int bn   = blockIdx.y * 128;

    const ushort_t* Bp = B;
    void* Cp = Cv; int ldC = Nsplit; int bnl = bn;
    if (B2 != nullptr && bn >= Nsplit) { Bp = B2; Cp = C2; ldC = N2; bnl = bn - Nsplit; }

    const int wm = (wave >> 1) * 64;
    const int wn = (wave & 1) * 64;

    const int lp   = lane ^ ((lane >> 3) & 7);
    const int prow = lp >> 3;
    const int psub = lp & 7;
    const ushort_t* aSrc[4];
    const ushort_t* bSrc[4];
    #pragma unroll
    for (int i = 0; i < 4; ++i) {
        int r = wave * 32 + i * 8 + prow;
        aSrc[i] = A  + (size_t)(bm  + r) * K + psub * 8;
        bSrc[i] = Bp + (size_t)(bnl + r) * K + psub * 8;
    }
    const int ldsOff = wave * 4096;

    f32x4 acc[4][4] = {};
    const int nk = K >> 6;

    #pragma unroll
    for (int i = 0; i < 4; ++i) {
        gld16(&sA[0][ldsOff + i * 1024], aSrc[i]);
        gld16(&sB[0][ldsOff + i * 1024], bSrc[i]);
    }

    int cur = 0;
    for (int k = 0; k < nk; ++k) {
        __syncthreads();
        if (k + 1 < nk) {
            const int ko = (k + 1) * 64;
            #pragma unroll
            for (int i = 0; i < 4; ++i) {
                gld16(&sA[cur ^ 1][ldsOff + i * 1024], aSrc[i] + ko);
                gld16(&sB[cur ^ 1][ldsOff + i * 1024], bSrc[i] + ko);
            }
        }
        #pragma unroll
        for (int kk = 0; kk < 2; ++kk) {
            V8 a[4], b[4];
            #pragma unroll
            for (int i2 = 0; i2 < 4; ++i2) {
                int row = wm + i2 * 16 + l15;
                a[i2].u = *(const u32x4*)(sA[cur] + ((row * 128 + kk * 64 + l4 * 16) ^ ((row & 7) << 4)));
                int col = wn + i2 * 16 + l15;
                b[i2].u = *(const u32x4*)(sB[cur] + ((col * 128 + kk * 64 + l4 * 16) ^ ((col & 7) << 4)));
            }
            #pragma unroll
            for (int i2 = 0; i2 < 4; ++i2)
                #pragma unroll
                for (int j = 0; j < 4; ++j)
                    acc[i2][j] = __builtin_amdgcn_mfma_f32_16x16x32_bf16(a[i2].b, b[j].b, acc[i2][j], 0, 0, 0);
        }
        cur ^= 1;
    }

    #pragma unroll
    for (int i = 0; i < 4; ++i)
        #pragma unroll
        for (int j = 0; j < 4; ++j)
            #pragma unroll
            for (int r = 0; r < 4; ++r) {
                int rowg = bm + wm + i * 16 + l4 * 4 + r;
                int colg = bnl + wn + j * 16 + l15;
                if constexpr (OUT_F32)
                    ((float*)Cp)[(size_t)rowg * ldC + colg] = acc[i][j][r];
                else
                    ((ushort_t*)Cp)[(size_t)rowg * ldC + colg] = f2b(acc[i][j][r]);
            }
}

// ---------------------------------------------------------------------------
// Fused RMSNorm + RoPE (unchanged).
// ---------------------------------------------------------------------------
__global__ __launch_bounds__(256) void norm_rope2(
    ushort_t* __restrict__ Qb, ushort_t* __restrict__ KVb,
    const float* __restrict__ QW, const float* __restrict__ KW,
    const float* __restrict__ FC, const float* __restrict__ FS)
{
    const int b    = blockIdx.x;
    const bool isK = b >= 2048;
    const int t    = b & 2047;
    const int tid  = threadIdx.x;
    const int h    = tid >> 4;
    const int sub  = tid & 15;

    ushort_t* X      = isK ? KVb : Qb;
    const float* W   = isK ? KW : QW;
    const int stride = isK ? 4096 : 2048;

    ushort_t* p = X + (size_t)t * stride + h * HD + sub * 8;
    V8 v; v.u = *(const u32x4*)p;
    float f[8];
    #pragma unroll
    for (int e = 0; e < 8; ++e) f[e] = b2f((ushort_t)v.s[e]);

    float ss = 0.f;
    #pragma unroll
    for (int e = 0; e < 8; ++e) ss += f[e] * f[e];
    ss += __shfl_xor(ss, 1);
    ss += __shfl_xor(ss, 2);
    ss += __shfl_xor(ss, 4);
    ss += __shfl_xor(ss, 8);
    float inv = rsqrtf(ss * (1.0f / 128.0f) + 1e-6f);

    float outv[8];
    #pragma unroll
    for (int k = 0; k < 4; ++k) {
        float c  = FC[(size_t)t * 64 + sub * 4 + k];
        float s  = FS[(size_t)t * 64 + sub * 4 + k];
        float w0 = W[sub * 8 + 2 * k];
        float w1 = W[sub * 8 + 2 * k + 1];
        float re = f[2 * k] * inv * w0;
        float im = f[2 * k + 1] * inv * w1;
        outv[2 * k]     = re * c - im * s;
        outv[2 * k + 1] = re * s + im * c;
    }
    V8 o;
    #pragma unroll
    for (int e = 0; e < 8; ++e) o.s[e] = (short)f2b(outv[e]);
    *(u32x4*)p = o.u;
}

// ---------------------------------------------------------------------------
// Causal flash attention, 512 thr = 4 kv-groups x 2 waves(32 q), 32x32 MFMA.
// This round: __launch_bounds__(512,1) (VGPR budget 256 — the 128 default
// spilled 13 MB, round 8) and T14 async staging: K AND V reg-prefetched
// right after the tile-ready barrier, LDS-written after the compute-done
// barrier, so HBM latency hides under compute. Single-buffered 128 KB LDS.
// ---------------------------------------------------------------------------
__global__ __launch_bounds__(512, 1) void attn_kernel(
    const ushort_t* __restrict__ Q,
    const ushort_t* __restrict__ KV,
    ushort_t* __restrict__ O)
{
    __shared__ __align__(16) char sAll[131072];

    const int id    = blockIdx.x;
    const int xcd   = id & 7;
    const int slot  = id >> 3;
    const int h     = xcd * 2 + (slot >> 4);
    const int pairb = slot & 15;

    const int tid  = threadIdx.x;
    const int gid  = tid >> 7;        // kv-split group 0..3
    const int wq   = (tid >> 6) & 1;  // q-strip (32 rows) within group
    const int lane = tid & 63;
    const int q31  = lane & 31;
    const int hi   = lane >> 5;
    const int t127 = tid & 127;

    char* sK = sAll + gid * 32768;           // [64 kv][128 d] bf16, swizzled
    char* sV = sAll + gid * 32768 + 16384;   // [128 d][64 kv] bf16, swizzled

    // V staging: thread owns d-pair (vd0, vd0+1) and a 32-kv half
    const int vd0 = (t127 & 63) * 2;
    const int vkh = (t127 >> 6) * 32;
    // K staging: thread covers rows r*8 + krow_, 16B chunk kcol
    const int krow_ = (t127 >> 6) * 4 + ((lane & 63) >> 4);   // 0..7
    const int kcol  = lane & 15;

    const float scale = 0.08838834764831845f;  // 1/sqrt(128)
    unsigned vreg[32];
    u32x4 kreg[8];

    float* aO[3]; float* aM[3]; float* aL[3];
    #pragma unroll
    for (int g = 0; g < 3; ++g) {
        aO[g] = (float*)(sAll + g * 36864);
        aM[g] = (float*)(sAll + g * 36864 + 34816);
        aL[g] = (float*)(sAll + g * 36864 + 35072);
    }

    #pragma unroll
    for (int phase = 0; phase < 2; ++phase) {
        const int jt  = phase ? (31 - pairb) : pairb;
        const int q0w = jt * 64 + wq * 32;

        V8 qf[8];
        #pragma unroll
        for (int kk = 0; kk < 8; ++kk)
            qf[kk].u = *(const u32x4*)(Q + (size_t)(q0w + q31) * DIM + h * HD + kk * 16 + hi * 8);

        f32x16 ot[4] = {};   // O^T: col=q31, rows d = db*32 + rmap(r,hi)
        float mrow = -1e30f, lrow = 0.f;

        const int n_g  = (jt >= gid) ? ((jt - gid) >> 2) + 1 : 0;
        const int nMax = (jt >> 2) + 1;

        if (n_g > 0) {
            const int kv0 = gid * 64;
            #pragma unroll
            for (int j = 0; j < 32; ++j)
                vreg[j] = *(const unsigned*)(KV + (size_t)(kv0 + vkh + j) * (2 * DIM) + DIM + h * HD + vd0);
            #pragma unroll
            for (int r = 0; r < 8; ++r)
                kreg[r] = *(const u32x4*)(KV + (size_t)(kv0 + r * 8 + krow_) * (2 * DIM) + h * HD + kcol * 8);
        }

        for (int s = 0; s < nMax; ++s) {
            __syncthreads();   // previous tile's compute finished everywhere
            if (s < n_g) {
                // V: reg-transposed, swizzled ds_write
                #pragma unroll
                for (int half = 0; half < 2; ++half) {
                    const int row = vd0 + half;
                    #pragma unroll
                    for (int c = 0; c < 4; ++c) {
                        V8 w;
                        #pragma unroll
                        for (int e = 0; e < 8; ++e)
                            w.s[e] = (short)(half ? (vreg[c * 8 + e] >> 16)
                                                  : (vreg[c * 8 + e] & 0xFFFFu));
                        *(u32x4*)(sV + ((row * 128 + vkh * 2 + c * 16) ^ ((row & 7) << 4))) = w.u;
                    }
                }
                // K: direct swizzled ds_write (row&7 == krow_)
                #pragma unroll
                for (int r = 0; r < 8; ++r) {
                    const int row = r * 8 + krow_;
                    *(u32x4*)(sK + ((row * 256 + kcol * 16) ^ ((krow_ & 7) << 4))) = kreg[r];
                }
            }
            __syncthreads();   // tile ready
            if (s + 1 < n_g) {  // early-issue next tile's loads: fly across compute
                const int kv0n = (4 * (s + 1) + gid) * 64;
                #pragma unroll
                for (int j = 0; j < 32; ++j)
                    vreg[j] = *(const unsigned*)(KV + (size_t)(kv0n + vkh + j) * (2 * DIM) + DIM + h * HD + vd0);
                #pragma unroll
                for (int r = 0; r < 8; ++r)
                    kreg[r] = *(const u32x4*)(KV + (size_t)(kv0n + r * 8 + krow_) * (2 * DIM) + h * HD + kcol * 8);
            }

            if (s < n_g) {
                const int tcur = 4 * s + gid;
                const int kv0  = tcur * 64;

                // ---- S^T = K Q^T (32x32x16) ----
                f32x16 sacc0 = {}, sacc1 = {};
                __builtin_amdgcn_s_setprio(1);
                #pragma unroll
                for (int kk = 0; kk < 8; ++kk) {
                    V8 kf0, kf1;
                    kf0.u = *(const u32x4*)(sK + ((q31 * 256 + kk * 32 + hi * 16) ^ ((q31 & 7) << 4)));
                    const int row1 = 32 + q31;
                    kf1.u = *(const u32x4*)(sK + ((row1 * 256 + kk * 32 + hi * 16) ^ ((row1 & 7) << 4)));
                    sacc0 = __builtin_amdgcn_mfma_f32_32x32x16_bf16(kf0.b, qf[kk].b, sacc0, 0, 0, 0);
                    sacc1 = __builtin_amdgcn_mfma_f32_32x32x16_bf16(kf1.b, qf[kk].b, sacc1, 0, 0, 0);
                }
                __builtin_amdgcn_s_setprio(0);

                // ---- softmax, lane-local in q = q31 ----
                float p0[16], p1[16];
                float tmax = -3e38f;
                const int qg = q0w + q31;
                #pragma unroll
                for (int r = 0; r < 16; ++r) {
                    const int rmap = (r & 3) + 8 * (r >> 2) + 4 * hi;
                    float s0 = sacc0[r] * scale;
                    float s1 = sacc1[r] * scale;
                    if (tcur == jt) {
                        if (kv0 + rmap > qg)      s0 = -1e30f;
                        if (kv0 + 32 + rmap > qg) s1 = -1e30f;
                    }
                    p0[r] = s0; p1[r] = s1;
                    tmax = fmaxf(tmax, fmaxf(s0, s1));
                }
                tmax = fmaxf(tmax, __shfl_xor(tmax, 32));
                const float mnew = fmaxf(mrow, tmax);
                const float corr = __expf(mrow - mnew);
                mrow = mnew;
                float rs = 0.f;
                #pragma unroll
                for (int r = 0; r < 16; ++r) {
                    p0[r] = __expf(p0[r] - mnew);
                    p1[r] = __expf(p1[r] - mnew);
                    rs += p0[r] + p1[r];
                }
                rs += __shfl_xor(rs, 32);
                lrow = lrow * corr + rs;

                #pragma unroll
                for (int db = 0; db < 4; ++db)
                    #pragma unroll
                    for (int r = 0; r < 16; ++r)
                        ot[db][r] *= corr;

                // ---- P B-fragments via shfl_xor(32) ----
                V8 pf[4];
                #pragma unroll
                for (int kb = 0; kb < 4; ++kb) {
                    const float* pp = (kb >> 1) ? p1 : p0;
                    const int R0 = (kb & 1) * 8;
                    unsigned cA = pk2(pp[R0 + 0], pp[R0 + 1]);
                    unsigned cB = pk2(pp[R0 + 2], pp[R0 + 3]);
                    unsigned cC = pk2(pp[R0 + 4], pp[R0 + 5]);
                    unsigned cD = pk2(pp[R0 + 6], pp[R0 + 7]);
                    unsigned sA_ = __shfl_xor(cA, 32);
                    unsigned sB_ = __shfl_xor(cB, 32);
                    unsigned sC_ = __shfl_xor(cC, 32);
                    unsigned sD_ = __shfl_xor(cD, 32);
                    pf[kb].u[0] = hi ? sC_ : cA;
                    pf[kb].u[1] = hi ? sD_ : cB;
                    pf[kb].u[2] = hi ? cC : sA_;
                    pf[kb].u[3] = hi ? cD : sB_;
                }

                // ---- O^T += V^T P (32x32x16) ----
                __builtin_amdgcn_s_setprio(1);
                #pragma unroll
                for (int db = 0; db < 4; ++db) {
                    const int d = db * 32 + q31;
                    #pragma unroll
                    for (int kb = 0; kb < 4; ++kb) {
                        V8 vf;
                        vf.u = *(const u32x4*)(sV + ((d * 128 + kb * 32 + hi * 16) ^ ((d & 7) << 4)));
                        ot[db] = __builtin_amdgcn_mfma_f32_32x32x16_bf16(vf.b, pf[kb].b, ot[db], 0, 0, 0);
                    }
                }
                __builtin_amdgcn_s_setprio(0);
            }
        }

        // ---- 4-way merge ----
        __syncthreads();
        const int qloc = wq * 32 + q31;
        if (gid >= 1) {
            float* mO = aO[gid - 1];
            #pragma unroll
            for (int db = 0; db < 4; ++db)
                #pragma unroll
                for (int rg = 0; rg < 4; ++rg) {
                    f32x4 t4 = { ot[db][rg * 4 + 0], ot[db][rg * 4 + 1],
                                 ot[db][rg * 4 + 2], ot[db][rg * 4 + 3] };
                    *(f32x4*)(mO + qloc * 136 + db * 32 + rg * 8 + hi * 4) = t4;
                }
            if (hi == 0) { aM[gid - 1][qloc] = mrow; aL[gid - 1][qloc] = lrow; }
        }
        __syncthreads();
        if (gid == 0) {
            const float m1 = aM[0][qloc], m2 = aM[1][qloc], m3 = aM[2][qloc];
            const float l1 = aL[0][qloc], l2 = aL[1][qloc], l3 = aL[2][qloc];
            const float mt = fmaxf(fmaxf(mrow, m1), fmaxf(m2, m3));
            const float c0 = __expf(mrow - mt), c1 = __expf(m1 - mt);
            const float c2 = __expf(m2 - mt),  c3 = __expf(m3 - mt);
            const float li = 1.f / (lrow * c0 + l1 * c1 + l2 * c2 + l3 * c3);
            const int qg = jt * 64 + qloc;
            #pragma unroll
            for (int db = 0; db < 4; ++db)
                #pragma unroll
                for (int rg = 0; rg < 4; ++rg) {
                    const int off = qloc * 136 + db * 32 + rg * 8 + hi * 4;
                    f32x4 v1 = *(const f32x4*)(aO[0] + off);
                    f32x4 v2 = *(const f32x4*)(aO[1] + off);
                    f32x4 v3 = *(const f32x4*)(aO[2] + off);
                    float vv[4];
                    #pragma unroll
                    for (int j = 0; j < 4; ++j)
                        vv[j] = (ot[db][rg * 4 + j] * c0 + v1[j] * c1 + v2[j] * c2 + v3[j] * c3) * li;
                    u32x2 w;
                    w[0] = pk2(vv[0], vv[1]);
                    w[1] = pk2(vv[2], vv[3]);
                    *(u32x2*)(O + (size_t)qg * DIM + h * HD + db * 32 + rg * 8 + hi * 4) = w;
                }
        }
        __syncthreads();   // phase seam
    }
}

// ---------------------------------------------------------------------------
extern "C" void kernel_launch(void* const* d_in, const int* in_sizes, int n_in,
                              void* d_out, int out_size, void* d_ws, size_t ws_size,
                              hipStream_t stream)
{
    const float* x    = (const float*)d_in[0];
    const float* wq   = (const float*)d_in[1];
    const float* wkvd = (const float*)d_in[2];
    const float* wkvu = (const float*)d_in[3];
    const float* wo   = (const float*)d_in[4];
    const float* qnw  = (const float*)d_in[5];
    const float* knw  = (const float*)d_in[6];
    const float* fc   = (const float*)d_in[7];
    const float* fs   = (const float*)d_in[8];
    float* out = (float*)d_out;

    char* ws = (char*)d_ws;
    const size_t MB = 1024 * 1024;
    ushort_t* xb    = (ushort_t*)(ws);
    ushort_t* att   = (ushort_t*)(ws);            // alias: xb dead after QKV gemm
    ushort_t* Qb    = (ushort_t*)(ws + 8  * MB);
    ushort_t* wqb   = (ushort_t*)(ws + 16 * MB);
    ushort_t* wkvdb = (ushort_t*)(ws + 24 * MB);
    ushort_t* kvb   = (ushort_t*)(ws + 16 * MB);  // alias: weights dead after QKV gemm
    ushort_t* lat   = (ushort_t*)(ws + 32 * MB);
    ushort_t* wkvub = (ushort_t*)(ws + 34 * MB);
    ushort_t* wob   = (ushort_t*)(ws + 38 * MB);

    cvtk<<<dim3(2048), dim3(256), 0, stream>>>(x, wq, wkvd, wkvu, wo,
                                               xb, wqb, wkvdb, wkvub, wob);
    gemm_nt<false><<<dim3(16, 20), dim3(256), 0, stream>>>(xb, wqb, Qb, 2048, 2048,
                                                           wkvdb, lat, 2048, 512);
    gemm_nt<false><<<dim3(16, 32), dim3(256), 0, stream>>>(lat, wkvub, kvb, 2048, 512,
                                                           nullptr, nullptr, 4096, 0);
    norm_rope2<<<dim3(4096), dim3(256), 0, stream>>>(Qb, kvb, qnw, knw, fc, fs);
    attn_kernel<<<dim3(256), dim3(512), 0, stream>>>(Qb, kvb, att);
    gemm_nt<true><<<dim3(16, 16), dim3(256), 0, stream>>>(att, wob, out, 2048, 2048,
                                                          nullptr, nullptr, 2048, 0);
}

// Round 10
// 174.269 us; speedup vs baseline: 1.3176x; 1.3176x over previous
//
#include <hip/hip_runtime.h>

#define T_SEQ 2048
#define DIM   2048
#define NH    16
#define HD    128
#define KVR   512

typedef unsigned short ushort_t;
typedef __attribute__((ext_vector_type(8))) short   short8;
typedef __attribute__((ext_vector_type(8))) __bf16  bf16x8;
typedef __attribute__((ext_vector_type(4))) float   f32x4;
typedef __attribute__((ext_vector_type(4))) unsigned int u32x4;

union V8 { short8 s; bf16x8 b; u32x4 u; };

__device__ inline float b2f(ushort_t u) {
    union { unsigned u; float f; } x; x.u = ((unsigned)u) << 16; return x.f;
}
__device__ inline ushort_t f2b(float f) {
    union { float f; unsigned u; } x; x.f = f;
    unsigned r = x.u + 0x7FFFu + ((x.u >> 16) & 1u);
    return (ushort_t)(r >> 16);
}

__device__ __forceinline__ void gld16(char* lds, const ushort_t* g) {
    __builtin_amdgcn_global_load_lds(
        (const __attribute__((address_space(1))) unsigned int*)g,
        (__attribute__((address_space(3))) unsigned int*)lds,
        16, 0, 0);
}

// ---------------------------------------------------------------------------
// Batched f32 -> bf16 conversion (unchanged).
// ---------------------------------------------------------------------------
__global__ __launch_bounds__(256) void cvtk(
    const float* __restrict__ a0, const float* __restrict__ a1,
    const float* __restrict__ a2, const float* __restrict__ a3,
    const float* __restrict__ a4,
    ushort_t* __restrict__ b0, ushort_t* __restrict__ b1,
    ushort_t* __restrict__ b2, ushort_t* __restrict__ b3,
    ushort_t* __restrict__ b4)
{
    const int N0 = 524288, N1 = 1048576, N2 = 1179648, N3 = 1441792, N4 = 1966080;
    for (int c = blockIdx.x * blockDim.x + threadIdx.x; c < N4; c += gridDim.x * blockDim.x) {
        const float* s; ushort_t* d; int off;
        if      (c < N0) { s = a0; d = b0; off = c; }
        else if (c < N1) { s = a1; d = b1; off = c - N0; }
        else if (c < N2) { s = a2; d = b2; off = c - N1; }
        else if (c < N3) { s = a3; d = b3; off = c - N2; }
        else             { s = a4; d = b4; off = c - N3; }
        f32x4 lo = *(const f32x4*)(s + (size_t)off * 8);
        f32x4 hi = *(const f32x4*)(s + (size_t)off * 8 + 4);
        V8 v;
        #pragma unroll
        for (int e = 0; e < 4; ++e) { v.b[e] = (__bf16)lo[e]; v.b[e + 4] = (__bf16)hi[e]; }
        *(u32x4*)(d + (size_t)off * 8) = v.u;
    }
}

// ---------------------------------------------------------------------------
// NT GEMM, all-bf16 inputs. This round: + XCD-aware chunked block swizzle
// (T1) — blocks sharing a B-panel land on the same XCD so B stays
// L2-resident (grids 320/512/256, all divisible by 8 -> bijective).
// ---------------------------------------------------------------------------
template <bool OUT_F32>
__global__ __launch_bounds__(256, 2) void gemm_nt(
    const ushort_t* __restrict__ A, const ushort_t* __restrict__ B,
    void* __restrict__ Cv, int M, int K,
    const ushort_t* __restrict__ B2, void* __restrict__ C2, int Nsplit, int N2)
{
    __shared__ __align__(16) char sA[2][16384];
    __shared__ __align__(16) char sB[2][16384];

    const int tid  = threadIdx.x;
    const int wave = tid >> 6;
    const int lane = tid & 63;
    const int l15  = lane & 15;
    const int l4   = lane >> 4;

    // XCD swizzle: hw block i runs on XCD i%8; give each XCD a contiguous
    // chunk of work ids (bx-fast) so 16 consecutive blocks share one B-panel.
    const int gridX = gridDim.x;
    int idlin = blockIdx.y * gridX + blockIdx.x;
    const int cpx = (gridX * gridDim.y) >> 3;
    idlin = (idlin & 7) * cpx + (idlin >> 3);
    const int bm = (idlin % gridX) * 128;
    const int bn = (idlin / gridX) * 128;

    const ushort_t* Bp = B;
    void* Cp = Cv; int ldC = Nsplit; int bnl = bn;
    if (B2 != nullptr && bn >= Nsplit) { Bp = B2; Cp = C2; ldC = N2; bnl = bn - Nsplit; }

    const int wm = (wave >> 1) * 64;
    const int wn = (wave & 1) * 64;

    const int lp   = lane ^ ((lane >> 3) & 7);
    const int prow = lp >> 3;
    const int psub = lp & 7;
    const ushort_t* aSrc[4];
    const ushort_t* bSrc[4];
    #pragma unroll
    for (int i = 0; i < 4; ++i) {
        int r = wave * 32 + i * 8 + prow;
        aSrc[i] = A  + (size_t)(bm  + r) * K + psub * 8;
        bSrc[i] = Bp + (size_t)(bnl + r) * K + psub * 8;
    }
    const int ldsOff = wave * 4096;

    f32x4 acc[4][4] = {};
    const int nk = K >> 6;

    #pragma unroll
    for (int i = 0; i < 4; ++i) {
        gld16(&sA[0][ldsOff + i * 1024], aSrc[i]);
        gld16(&sB[0][ldsOff + i * 1024], bSrc[i]);
    }

    int cur = 0;
    for (int k = 0; k < nk; ++k) {
        __syncthreads();
        if (k + 1 < nk) {
            const int ko = (k + 1) * 64;
            #pragma unroll
            for (int i = 0; i < 4; ++i) {
                gld16(&sA[cur ^ 1][ldsOff + i * 1024], aSrc[i] + ko);
                gld16(&sB[cur ^ 1][ldsOff + i * 1024], bSrc[i] + ko);
            }
        }
        #pragma unroll
        for (int kk = 0; kk < 2; ++kk) {
            V8 a[4], b[4];
            #pragma unroll
            for (int i2 = 0; i2 < 4; ++i2) {
                int row = wm + i2 * 16 + l15;
                a[i2].u = *(const u32x4*)(sA[cur] + ((row * 128 + kk * 64 + l4 * 16) ^ ((row & 7) << 4)));
                int col = wn + i2 * 16 + l15;
                b[i2].u = *(const u32x4*)(sB[cur] + ((col * 128 + kk * 64 + l4 * 16) ^ ((col & 7) << 4)));
            }
            #pragma unroll
            for (int i2 = 0; i2 < 4; ++i2)
                #pragma unroll
                for (int j = 0; j < 4; ++j)
                    acc[i2][j] = __builtin_amdgcn_mfma_f32_16x16x32_bf16(a[i2].b, b[j].b, acc[i2][j], 0, 0, 0);
        }
        cur ^= 1;
    }

    #pragma unroll
    for (int i = 0; i < 4; ++i)
        #pragma unroll
        for (int j = 0; j < 4; ++j)
            #pragma unroll
            for (int r = 0; r < 4; ++r) {
                int rowg = bm + wm + i * 16 + l4 * 4 + r;
                int colg = bnl + wn + j * 16 + l15;
                if constexpr (OUT_F32)
                    ((float*)Cp)[(size_t)rowg * ldC + colg] = acc[i][j][r];
                else
                    ((ushort_t*)Cp)[(size_t)rowg * ldC + colg] = f2b(acc[i][j][r]);
            }
}

// ---------------------------------------------------------------------------
// Fused RMSNorm + RoPE (unchanged).
// ---------------------------------------------------------------------------
__global__ __launch_bounds__(256) void norm_rope2(
    ushort_t* __restrict__ Qb, ushort_t* __restrict__ KVb,
    const float* __restrict__ QW, const float* __restrict__ KW,
    const float* __restrict__ FC, const float* __restrict__ FS)
{
    const int b    = blockIdx.x;
    const bool isK = b >= 2048;
    const int t    = b & 2047;
    const int tid  = threadIdx.x;
    const int h    = tid >> 4;
    const int sub  = tid & 15;

    ushort_t* X      = isK ? KVb : Qb;
    const float* W   = isK ? KW : QW;
    const int stride = isK ? 4096 : 2048;

    ushort_t* p = X + (size_t)t * stride + h * HD + sub * 8;
    V8 v; v.u = *(const u32x4*)p;
    float f[8];
    #pragma unroll
    for (int e = 0; e < 8; ++e) f[e] = b2f((ushort_t)v.s[e]);

    float ss = 0.f;
    #pragma unroll
    for (int e = 0; e < 8; ++e) ss += f[e] * f[e];
    ss += __shfl_xor(ss, 1);
    ss += __shfl_xor(ss, 2);
    ss += __shfl_xor(ss, 4);
    ss += __shfl_xor(ss, 8);
    float inv = rsqrtf(ss * (1.0f / 128.0f) + 1e-6f);

    float outv[8];
    #pragma unroll
    for (int k = 0; k < 4; ++k) {
        float c  = FC[(size_t)t * 64 + sub * 4 + k];
        float s  = FS[(size_t)t * 64 + sub * 4 + k];
        float w0 = W[sub * 8 + 2 * k];
        float w1 = W[sub * 8 + 2 * k + 1];
        float re = f[2 * k] * inv * w0;
        float im = f[2 * k + 1] * inv * w1;
        outv[2 * k]     = re * c - im * s;
        outv[2 * k + 1] = re * s + im * c;
    }
    V8 o;
    #pragma unroll
    for (int e = 0; e < 8; ++e) o.s[e] = (short)f2b(outv[e]);
    *(u32x4*)p = o.u;
}

// ---------------------------------------------------------------------------
// Causal flash attention — round-4 structure (measured 59.9 us, VGPR 104,
// no spill): 512 thr = 2 kv-groups x 4 waves(16 q), 16x16 MFMA, K/V
// double-buffered per group, P rebuilt in-register, 2-way LDS merge.
// This round's edits only: exp2-domain softmax (log2e folded into scale),
// T13 defer-max (wave-uniform rescale skip, THR=8*log2e), setprio on MFMA.
// NOTE: keep 512-thr blocks; 1024-thr pins VGPR budget to 64 and spills
// (rounds 6-7); (512,*) launch-bounds tweaks don't raise the 128 budget
// (rounds 8-9).
// ---------------------------------------------------------------------------
#define STAGE_LOAD(kv0) do { \
  _Pragma("unroll") for (int rr = 0; rr < 4; ++rr) \
    kreg[rr] = *(const u32x4*)(KV + (size_t)((kv0) + krow[rr]) * (2 * DIM) + h * HD + kc8 * 8); \
  _Pragma("unroll") for (int rr = 0; rr < 2; ++rr) \
    _Pragma("unroll") for (int e = 0; e < 8; ++e) \
      vreg[rr][e] = *(const unsigned*)(KV + (size_t)((kv0) + vkvb[rr] * 8 + e) * (2 * DIM) + DIM + h * HD + vd); \
} while (0)

#define STAGE_WRITE(sKb, sVb) do { \
  _Pragma("unroll") for (int rr = 0; rr < 4; ++rr) \
    *(u32x4*)((sKb) + ((krow[rr] * 256 + kc8 * 16) ^ ((krow[rr] & 7) << 4))) = kreg[rr]; \
  _Pragma("unroll") for (int rr = 0; rr < 2; ++rr) { \
    V8 lo, hi; \
    _Pragma("unroll") for (int e = 0; e < 8; ++e) { \
      lo.s[e] = (short)(vreg[rr][e] & 0xFFFFu); hi.s[e] = (short)(vreg[rr][e] >> 16); } \
    *(u32x4*)((sVb) + ((vd * 128 + vkvb[rr] * 16) ^ ((vd & 7) << 4)))             = lo.u; \
    *(u32x4*)((sVb) + (((vd + 1) * 128 + vkvb[rr] * 16) ^ (((vd + 1) & 7) << 4))) = hi.u; \
  } \
} while (0)

__global__ __launch_bounds__(512) void attn_kernel(
    const ushort_t* __restrict__ Q,
    const ushort_t* __restrict__ KV,
    ushort_t* __restrict__ O)
{
    __shared__ __align__(16) char sAll[131072];

    const int id    = blockIdx.x;
    const int xcd   = id & 7;
    const int slot  = id >> 3;
    const int h     = xcd * 2 + (slot >> 4);
    const int pairb = slot & 15;

    const int tid   = threadIdx.x;
    const int gid   = tid >> 8;            // 0: even tiles, 1: odd tiles
    const int wtid  = tid & 255;
    const int wave4 = wtid >> 6;
    const int lane  = tid & 63;
    const int Qq    = lane & 15;
    const int G     = lane >> 4;

    char* gbase = sAll + gid * 65536;      // [K0 16K][K1 16K][V0 16K][V1 16K]

    const int krow[4] = { (0*256 + wtid) >> 4, (1*256 + wtid) >> 4,
                          (2*256 + wtid) >> 4, (3*256 + wtid) >> 4 };
    const int kc8 = wtid & 15;
    const int vd  = lane * 2;
    const int vkvb[2] = { wave4, 4 + wave4 };

    // exp2-domain: scale' = (1/sqrt(128)) * log2(e); THR' = 8 * log2(e)
    const float scale2 = 0.08838834764831845f * 1.4426950408889634f;
    const float THR2   = 11.541560327111707f;

    u32x4 kreg[4];
    unsigned vreg[2][8];

    #pragma unroll
    for (int phase = 0; phase < 2; ++phase) {
        const int jt  = phase ? (31 - pairb) : pairb;
        const int q0w = jt * 64 + wave4 * 16;

        V8 qf[4];
        #pragma unroll
        for (int kk = 0; kk < 4; ++kk)
            qf[kk].u = *(const u32x4*)(Q + (size_t)(q0w + Qq) * DIM + h * HD + kk * 32 + G * 8);

        f32x4 o[8] = {};
        float mrow = -1e30f, lrow = 0.f;

        const int n_g = (jt >= gid) ? ((jt - gid) >> 1) + 1 : 0;
        const int nA  = (jt >> 1) + 1;

        if (n_g > 0) {
            STAGE_LOAD(gid * 64);
            STAGE_WRITE(gbase, gbase + 32768);
        }

        int cur = 0;
        for (int s = 0; s < nA; ++s) {
            __syncthreads();

            const bool pf = (s + 1 < n_g);
            if (pf) STAGE_LOAD((2 * (s + 1) + gid) * 64);

            if (s < n_g) {
                const int tcur = 2 * s + gid;
                const int kv0  = tcur * 64;
                char* sKb = gbase + cur * 16384;
                char* sVb = gbase + 32768 + cur * 16384;

                // S^T = K Q^T : lane q = Qq, kv = cb*16 + G*4 + r
                f32x4 sacc[4] = {};
                __builtin_amdgcn_s_setprio(1);
                #pragma unroll
                for (int kk = 0; kk < 4; ++kk) {
                    #pragma unroll
                    for (int cb = 0; cb < 4; ++cb) {
                        int row = cb * 16 + Qq;
                        V8 kf;
                        kf.u = *(const u32x4*)(sKb + ((row * 256 + kk * 64 + G * 16) ^ ((row & 7) << 4)));
                        sacc[cb] = __builtin_amdgcn_mfma_f32_16x16x32_bf16(kf.b, qf[kk].b, sacc[cb], 0, 0, 0);
                    }
                }
                __builtin_amdgcn_s_setprio(0);

                // softmax in exp2 domain (lane-local in q)
                float p[4][4];
                float tmax = -3e38f;
                const int qg = q0w + Qq;
                #pragma unroll
                for (int cb = 0; cb < 4; ++cb)
                    #pragma unroll
                    for (int r = 0; r < 4; ++r) {
                        float s2 = sacc[cb][r] * scale2;
                        if (tcur == jt) {
                            int kvg = kv0 + cb * 16 + G * 4 + r;
                            if (kvg > qg) s2 = -1e30f;
                        }
                        p[cb][r] = s2;
                        tmax = fmaxf(tmax, s2);
                    }
                tmax = fmaxf(tmax, __shfl_xor(tmax, 16));
                tmax = fmaxf(tmax, __shfl_xor(tmax, 32));

                // T13 defer-max: skip rescale when no q-row grew past THR
                const bool skip = __all(tmax - mrow <= THR2);
                float corr = 1.0f;
                if (!skip) {
                    const float mnew = fmaxf(mrow, tmax);
                    corr = exp2f(mrow - mnew);
                    mrow = mnew;
                }
                float rs = 0.f;
                #pragma unroll
                for (int cb = 0; cb < 4; ++cb)
                    #pragma unroll
                    for (int r = 0; r < 4; ++r) {
                        float e = exp2f(p[cb][r] - mrow);
                        p[cb][r] = e;
                        rs += e;
                    }
                rs += __shfl_xor(rs, 16);
                rs += __shfl_xor(rs, 32);
                lrow = lrow * corr + rs;

                unsigned pk[4][2];
                #pragma unroll
                for (int cb = 0; cb < 4; ++cb) {
                    pk[cb][0] = (unsigned)f2b(p[cb][0]) | ((unsigned)f2b(p[cb][1]) << 16);
                    pk[cb][1] = (unsigned)f2b(p[cb][2]) | ((unsigned)f2b(p[cb][3]) << 16);
                }

                if (!skip) {   // wave-uniform
                    float cf[4];
                    #pragma unroll
                    for (int r = 0; r < 4; ++r)
                        cf[r] = __shfl(corr, G * 4 + r);
                    #pragma unroll
                    for (int nb = 0; nb < 8; ++nb)
                        #pragma unroll
                        for (int r = 0; r < 4; ++r)
                            o[nb][r] *= cf[r];
                }

                // O += P V (P A-fragment rebuilt in-register)
                const int sLo = ((G & 1) * 2) * 16 + Qq;
                const int sHi = sLo + 16;
                const bool hiC = (G >> 1);
                #pragma unroll
                for (int kk2 = 0; kk2 < 2; ++kk2) {
                    const int c0 = kk2 * 2, c1 = c0 + 1;
                    unsigned w0a = __shfl(pk[c0][0], sLo), w0b = __shfl(pk[c1][0], sLo);
                    unsigned w1a = __shfl(pk[c0][1], sLo), w1b = __shfl(pk[c1][1], sLo);
                    unsigned w2a = __shfl(pk[c0][0], sHi), w2b = __shfl(pk[c1][0], sHi);
                    unsigned w3a = __shfl(pk[c0][1], sHi), w3b = __shfl(pk[c1][1], sHi);
                    V8 pa;
                    pa.u[0] = hiC ? w0b : w0a;
                    pa.u[1] = hiC ? w1b : w1a;
                    pa.u[2] = hiC ? w2b : w2a;
                    pa.u[3] = hiC ? w3b : w3a;
                    __builtin_amdgcn_s_setprio(1);
                    #pragma unroll
                    for (int nb = 0; nb < 8; ++nb) {
                        int d = nb * 16 + Qq;
                        V8 vf;
                        vf.u = *(const u32x4*)(sVb + ((d * 128 + kk2 * 64 + G * 16) ^ ((d & 7) << 4)));
                        o[nb] = __builtin_amdgcn_mfma_f32_16x16x32_bf16(pa.b, vf.b, o[nb], 0, 0, 0);
                    }
                    __builtin_amdgcn_s_setprio(0);
                }
            }

            if (pf) STAGE_WRITE(gbase + (cur ^ 1) * 16384, gbase + 32768 + (cur ^ 1) * 16384);
            cur ^= 1;
        }

        // ---- merge group B into group A ----
        __syncthreads();
        float* mrg = (float*)sAll;               // [64 q][132 words] f32
        float* mlb = (float*)(sAll + 33792);     // [m:64][l:64]
        if (gid == 1) {
            #pragma unroll
            for (int nb = 0; nb < 8; ++nb)
                #pragma unroll
                for (int r = 0; r < 4; ++r) {
                    int qloc = wave4 * 16 + G * 4 + r;
                    mrg[qloc * 132 + nb * 16 + Qq] = o[nb][r];
                }
            if (G == 0) {
                int qloc = wave4 * 16 + Qq;
                mlb[qloc]      = mrow;
                mlb[64 + qloc] = lrow;
            }
        }
        __syncthreads();
        if (gid == 0) {
            int qloc0 = wave4 * 16 + Qq;
            float mB = mlb[qloc0], lB = mlb[64 + qloc0];
            float m  = fmaxf(mrow, mB);
            float cA = exp2f(mrow - m), cB = exp2f(mB - m);
            float linv = 1.f / (lrow * cA + lB * cB);
            float cAr[4], cBr[4], lir[4];
            #pragma unroll
            for (int r = 0; r < 4; ++r) {
                cAr[r] = __shfl(cA, G * 4 + r);
                cBr[r] = __shfl(cB, G * 4 + r);
                lir[r] = __shfl(linv, G * 4 + r);
            }
            #pragma unroll
            for (int nb = 0; nb < 8; ++nb)
                #pragma unroll
                for (int r = 0; r < 4; ++r) {
                    int qloc = wave4 * 16 + G * 4 + r;
                    float ob  = mrg[qloc * 132 + nb * 16 + Qq];
                    float val = (o[nb][r] * cAr[r] + ob * cBr[r]) * lir[r];
                    int qgr = jt * 64 + qloc;
                    O[(size_t)qgr * DIM + h * HD + nb * 16 + Qq] = f2b(val);
                }
        }
        __syncthreads();   // phase seam
    }
}

// ---------------------------------------------------------------------------
extern "C" void kernel_launch(void* const* d_in, const int* in_sizes, int n_in,
                              void* d_out, int out_size, void* d_ws, size_t ws_size,
                              hipStream_t stream)
{
    const float* x    = (const float*)d_in[0];
    const float* wq   = (const float*)d_in[1];
    const float* wkvd = (const float*)d_in[2];
    const float* wkvu = (const float*)d_in[3];
    const float* wo   = (const float*)d_in[4];
    const float* qnw  = (const float*)d_in[5];
    const float* knw  = (const float*)d_in[6];
    const float* fc   = (const float*)d_in[7];
    const float* fs   = (const float*)d_in[8];
    float* out = (float*)d_out;

    char* ws = (char*)d_ws;
    const size_t MB = 1024 * 1024;
    ushort_t* xb    = (ushort_t*)(ws);
    ushort_t* att   = (ushort_t*)(ws);            // alias: xb dead after QKV gemm
    ushort_t* Qb    = (ushort_t*)(ws + 8  * MB);
    ushort_t* wqb   = (ushort_t*)(ws + 16 * MB);
    ushort_t* wkvdb = (ushort_t*)(ws + 24 * MB);
    ushort_t* kvb   = (ushort_t*)(ws + 16 * MB);  // alias: weights dead after QKV gemm
    ushort_t* lat   = (ushort_t*)(ws + 32 * MB);
    ushort_t* wkvub = (ushort_t*)(ws + 34 * MB);
    ushort_t* wob   = (ushort_t*)(ws + 38 * MB);

    cvtk<<<dim3(2048), dim3(256), 0, stream>>>(x, wq, wkvd, wkvu, wo,
                                               xb, wqb, wkvdb, wkvub, wob);
    gemm_nt<false><<<dim3(16, 20), dim3(256), 0, stream>>>(xb, wqb, Qb, 2048, 2048,
                                                           wkvdb, lat, 2048, 512);
    gemm_nt<false><<<dim3(16, 32), dim3(256), 0, stream>>>(lat, wkvub, kvb, 2048, 512,
                                                           nullptr, nullptr, 4096, 0);
    norm_rope2<<<dim3(4096), dim3(256), 0, stream>>>(Qb, kvb, qnw, knw, fc, fs);
    attn_kernel<<<dim3(256), dim3(512), 0, stream>>>(Qb, kvb, att);
    gemm_nt<true><<<dim3(16, 16), dim3(256), 0, stream>>>(att, wob, out, 2048, 2048,
                                                          nullptr, nullptr, 2048, 0);
}

// Round 11
// 159.084 us; speedup vs baseline: 1.4434x; 1.0954x over previous
//
#include <hip/hip_runtime.h>

#define T_SEQ 2048
#define DIM   2048
#define NH    16
#define HD    128
#define KVR   512

typedef unsigned short ushort_t;
typedef __attribute__((ext_vector_type(8))) short   short8;
typedef __attribute__((ext_vector_type(8))) __bf16  bf16x8;
typedef __attribute__((ext_vector_type(4))) float   f32x4;
typedef __attribute__((ext_vector_type(4))) unsigned int u32x4;

union V8 { short8 s; bf16x8 b; u32x4 u; };

__device__ inline float b2f(ushort_t u) {
    union { unsigned u; float f; } x; x.u = ((unsigned)u) << 16; return x.f;
}
__device__ inline ushort_t f2b(float f) {
    union { float f; unsigned u; } x; x.f = f;
    unsigned r = x.u + 0x7FFFu + ((x.u >> 16) & 1u);
    return (ushort_t)(r >> 16);
}

__device__ __forceinline__ void gld16(char* lds, const ushort_t* g) {
    __builtin_amdgcn_global_load_lds(
        (const __attribute__((address_space(1))) unsigned int*)g,
        (__attribute__((address_space(3))) unsigned int*)lds,
        16, 0, 0);
}

// ---------------------------------------------------------------------------
// Batched f32 -> bf16 conversion (unchanged).
// ---------------------------------------------------------------------------
__global__ __launch_bounds__(256) void cvtk(
    const float* __restrict__ a0, const float* __restrict__ a1,
    const float* __restrict__ a2, const float* __restrict__ a3,
    const float* __restrict__ a4,
    ushort_t* __restrict__ b0, ushort_t* __restrict__ b1,
    ushort_t* __restrict__ b2, ushort_t* __restrict__ b3,
    ushort_t* __restrict__ b4)
{
    const int N0 = 524288, N1 = 1048576, N2 = 1179648, N3 = 1441792, N4 = 1966080;
    for (int c = blockIdx.x * blockDim.x + threadIdx.x; c < N4; c += gridDim.x * blockDim.x) {
        const float* s; ushort_t* d; int off;
        if      (c < N0) { s = a0; d = b0; off = c; }
        else if (c < N1) { s = a1; d = b1; off = c - N0; }
        else if (c < N2) { s = a2; d = b2; off = c - N1; }
        else if (c < N3) { s = a3; d = b3; off = c - N2; }
        else             { s = a4; d = b4; off = c - N3; }
        f32x4 lo = *(const f32x4*)(s + (size_t)off * 8);
        f32x4 hi = *(const f32x4*)(s + (size_t)off * 8 + 4);
        V8 v;
        #pragma unroll
        for (int e = 0; e < 4; ++e) { v.b[e] = (__bf16)lo[e]; v.b[e + 4] = (__bf16)hi[e]; }
        *(u32x4*)(d + (size_t)off * 8) = v.u;
    }
}

// ---------------------------------------------------------------------------
// Generalized NT GEMM, all-bf16 inputs. Tile BM x BN (BM,BN in {64,128}),
// 256 thr / 4 waves. Grids sized for >=2 balanced blocks/CU:
//   gemm1: 64x128 -> 640 blocks (+ fused lat output + fused Q rmsnorm/rope)
//   gemm2: 128x128 -> 512 blocks
//   gemm4: 128x64 -> 512 blocks
// Double-buffered global_load_lds staging, source pre-swizzled (rule #21).
// XCD-aware chunked swizzle (all grids % 8 == 0 -> bijective).
// ---------------------------------------------------------------------------
template <int BM, int BN, bool OUT_F32, bool NORMQ>
__global__ __launch_bounds__(256, 2) void gemm_nt(
    const ushort_t* __restrict__ A, const ushort_t* __restrict__ B,
    void* __restrict__ Cv, int M, int K,
    const ushort_t* __restrict__ B2, void* __restrict__ C2, int Nsplit, int N2,
    const float* __restrict__ NW, const float* __restrict__ FC,
    const float* __restrict__ FS)
{
    constexpr int GM = BM / 64;       // 1 or 2 wave rows
    constexpr int WN = BN * GM / 4;   // wave col width: 32 / 64 / 32
    constexpr int NJ = WN / 16;       // b-frags & acc cols
    constexpr int AR = BM / 32;       // A staging rounds
    constexpr int BR = BN / 32;       // B staging rounds

    __shared__ __align__(16) char sA[2][BM * 128];
    __shared__ __align__(16) char sB[2][BN * 128];

    const int tid  = threadIdx.x;
    const int wave = tid >> 6;
    const int lane = tid & 63;
    const int l15  = lane & 15;
    const int l4   = lane >> 4;

    // XCD swizzle: consecutive work-ids (bm-fast) share a B-panel on one XCD.
    const int gridX = gridDim.x;
    int idlin = blockIdx.y * gridX + blockIdx.x;
    const int cpx = (gridX * gridDim.y) >> 3;
    idlin = (idlin & 7) * cpx + (idlin >> 3);
    const int bm = (idlin % gridX) * BM;
    const int bn = (idlin / gridX) * BN;

    const ushort_t* Bp = B;
    void* Cp = Cv; int ldC = Nsplit; int bnl = bn;
    bool second = false;
    if (B2 != nullptr && bn >= Nsplit) { Bp = B2; Cp = C2; ldC = N2; bnl = bn - Nsplit; second = true; }

    const int wmo = (GM == 2) ? (wave >> 1) * 64 : 0;
    const int wno = (GM == 2) ? (wave & 1) * WN : wave * WN;

    const int lp   = lane ^ ((lane >> 3) & 7);
    const int prow = lp >> 3;
    const int psub = lp & 7;
    const ushort_t* aSrc[AR];
    const ushort_t* bSrc[BR];
    #pragma unroll
    for (int i = 0; i < AR; ++i) {
        int r = wave * (BM / 4) + i * 8 + prow;
        aSrc[i] = A + (size_t)(bm + r) * K + psub * 8;
    }
    #pragma unroll
    for (int i = 0; i < BR; ++i) {
        int r = wave * (BN / 4) + i * 8 + prow;
        bSrc[i] = Bp + (size_t)(bnl + r) * K + psub * 8;
    }
    const int ldsOffA = wave * (BM * 32);
    const int ldsOffB = wave * (BN * 32);

    f32x4 acc[4][NJ] = {};
    const int nk = K >> 6;

    #pragma unroll
    for (int i = 0; i < AR; ++i) gld16(&sA[0][ldsOffA + i * 1024], aSrc[i]);
    #pragma unroll
    for (int i = 0; i < BR; ++i) gld16(&sB[0][ldsOffB + i * 1024], bSrc[i]);

    int cur = 0;
    for (int k = 0; k < nk; ++k) {
        __syncthreads();
        if (k + 1 < nk) {
            const int ko = (k + 1) * 64;
            #pragma unroll
            for (int i = 0; i < AR; ++i) gld16(&sA[cur ^ 1][ldsOffA + i * 1024], aSrc[i] + ko);
            #pragma unroll
            for (int i = 0; i < BR; ++i) gld16(&sB[cur ^ 1][ldsOffB + i * 1024], bSrc[i] + ko);
        }
        #pragma unroll
        for (int kk = 0; kk < 2; ++kk) {
            V8 a[4], b[NJ];
            #pragma unroll
            for (int i2 = 0; i2 < 4; ++i2) {
                int row = wmo + i2 * 16 + l15;
                a[i2].u = *(const u32x4*)(sA[cur] + ((row * 128 + kk * 64 + l4 * 16) ^ ((row & 7) << 4)));
            }
            #pragma unroll
            for (int j = 0; j < NJ; ++j) {
                int col = wno + j * 16 + l15;
                b[j].u = *(const u32x4*)(sB[cur] + ((col * 128 + kk * 64 + l4 * 16) ^ ((col & 7) << 4)));
            }
            #pragma unroll
            for (int i2 = 0; i2 < 4; ++i2)
                #pragma unroll
                for (int j = 0; j < NJ; ++j)
                    acc[i2][j] = __builtin_amdgcn_mfma_f32_16x16x32_bf16(a[i2].b, b[j].b, acc[i2][j], 0, 0, 0);
        }
        cur ^= 1;
    }

    const bool doNorm = NORMQ && !second;   // block-uniform
    if (doNorm) {
        // fused RMSNorm + RoPE over the head dim (BN==128 head-aligned).
        // 1) per-row sum of squares: lane partial over its cols, reduce l15,
        //    combine 4 waves via LDS.
        __syncthreads();                      // k-loop reads of sA done
        float* sums = (float*)sA;             // [4][64]
        #pragma unroll
        for (int i = 0; i < 4; ++i)
            #pragma unroll
            for (int r = 0; r < 4; ++r) {
                float ss = 0.f;
                #pragma unroll
                for (int j = 0; j < NJ; ++j) ss += acc[i][j][r] * acc[i][j][r];
                ss += __shfl_xor(ss, 1);
                ss += __shfl_xor(ss, 2);
                ss += __shfl_xor(ss, 4);
                ss += __shfl_xor(ss, 8);
                if (l15 == 0) sums[wave * 64 + i * 16 + l4 * 4 + r] = ss;
            }
        __syncthreads();
        #pragma unroll
        for (int i = 0; i < 4; ++i)
            #pragma unroll
            for (int r = 0; r < 4; ++r) {
                const int rloc = i * 16 + l4 * 4 + r;
                const float tot = sums[rloc] + sums[64 + rloc] + sums[128 + rloc] + sums[192 + rloc];
                const float inv = rsqrtf(tot * (1.0f / 128.0f) + 1e-6f);
                const int t = bm + rloc;
                #pragma unroll
                for (int j = 0; j < NJ; ++j) {
                    const int col = wno + j * 16 + l15;       // 0..127 in-head
                    float v = acc[i][j][r] * inv * NW[col];
                    float partner = __shfl_xor(v, 1);
                    const float c = FC[(size_t)t * 64 + (col >> 1)];
                    const float s = FS[(size_t)t * 64 + (col >> 1)];
                    float outv = (l15 & 1) ? (partner * s + v * c)
                                           : (v * c - partner * s);
                    ((ushort_t*)Cp)[(size_t)t * ldC + bnl + col] = f2b(outv);
                }
            }
        return;
    }

    #pragma unroll
    for (int i = 0; i < 4; ++i)
        #pragma unroll
        for (int j = 0; j < NJ; ++j)
            #pragma unroll
            for (int r = 0; r < 4; ++r) {
                int rowg = bm + wmo + i * 16 + l4 * 4 + r;
                int colg = bnl + wno + j * 16 + l15;
                if constexpr (OUT_F32)
                    ((float*)Cp)[(size_t)rowg * ldC + colg] = acc[i][j][r];
                else
                    ((ushort_t*)Cp)[(size_t)rowg * ldC + colg] = f2b(acc[i][j][r]);
            }
}

// ---------------------------------------------------------------------------
// RMSNorm + RoPE for K only (Q now fused into gemm1 epilogue).
// ---------------------------------------------------------------------------
__global__ __launch_bounds__(256) void norm_ropeK(
    ushort_t* __restrict__ KVb, const float* __restrict__ KW,
    const float* __restrict__ FC, const float* __restrict__ FS)
{
    const int t   = blockIdx.x;
    const int tid = threadIdx.x;
    const int h   = tid >> 4;
    const int sub = tid & 15;

    ushort_t* p = KVb + (size_t)t * 4096 + h * HD + sub * 8;
    V8 v; v.u = *(const u32x4*)p;
    float f[8];
    #pragma unroll
    for (int e = 0; e < 8; ++e) f[e] = b2f((ushort_t)v.s[e]);

    float ss = 0.f;
    #pragma unroll
    for (int e = 0; e < 8; ++e) ss += f[e] * f[e];
    ss += __shfl_xor(ss, 1);
    ss += __shfl_xor(ss, 2);
    ss += __shfl_xor(ss, 4);
    ss += __shfl_xor(ss, 8);
    float inv = rsqrtf(ss * (1.0f / 128.0f) + 1e-6f);

    float outv[8];
    #pragma unroll
    for (int k = 0; k < 4; ++k) {
        float c  = FC[(size_t)t * 64 + sub * 4 + k];
        float s  = FS[(size_t)t * 64 + sub * 4 + k];
        float w0 = KW[sub * 8 + 2 * k];
        float w1 = KW[sub * 8 + 2 * k + 1];
        float re = f[2 * k] * inv * w0;
        float im = f[2 * k + 1] * inv * w1;
        outv[2 * k]     = re * c - im * s;
        outv[2 * k + 1] = re * s + im * c;
    }
    V8 o;
    #pragma unroll
    for (int e = 0; e < 8; ++e) o.s[e] = (short)f2b(outv[e]);
    *(u32x4*)p = o.u;
}

// ---------------------------------------------------------------------------
// Causal flash attention (unchanged from round 10: 62 us, VGPR 100).
// ---------------------------------------------------------------------------
#define STAGE_LOAD(kv0) do { \
  _Pragma("unroll") for (int rr = 0; rr < 4; ++rr) \
    kreg[rr] = *(const u32x4*)(KV + (size_t)((kv0) + krow[rr]) * (2 * DIM) + h * HD + kc8 * 8); \
  _Pragma("unroll") for (int rr = 0; rr < 2; ++rr) \
    _Pragma("unroll") for (int e = 0; e < 8; ++e) \
      vreg[rr][e] = *(const unsigned*)(KV + (size_t)((kv0) + vkvb[rr] * 8 + e) * (2 * DIM) + DIM + h * HD + vd); \
} while (0)

#define STAGE_WRITE(sKb, sVb) do { \
  _Pragma("unroll") for (int rr = 0; rr < 4; ++rr) \
    *(u32x4*)((sKb) + ((krow[rr] * 256 + kc8 * 16) ^ ((krow[rr] & 7) << 4))) = kreg[rr]; \
  _Pragma("unroll") for (int rr = 0; rr < 2; ++rr) { \
    V8 lo, hi; \
    _Pragma("unroll") for (int e = 0; e < 8; ++e) { \
      lo.s[e] = (short)(vreg[rr][e] & 0xFFFFu); hi.s[e] = (short)(vreg[rr][e] >> 16); } \
    *(u32x4*)((sVb) + ((vd * 128 + vkvb[rr] * 16) ^ ((vd & 7) << 4)))             = lo.u; \
    *(u32x4*)((sVb) + (((vd + 1) * 128 + vkvb[rr] * 16) ^ (((vd + 1) & 7) << 4))) = hi.u; \
  } \
} while (0)

__global__ __launch_bounds__(512) void attn_kernel(
    const ushort_t* __restrict__ Q,
    const ushort_t* __restrict__ KV,
    ushort_t* __restrict__ O)
{
    __shared__ __align__(16) char sAll[131072];

    const int id    = blockIdx.x;
    const int xcd   = id & 7;
    const int slot  = id >> 3;
    const int h     = xcd * 2 + (slot >> 4);
    const int pairb = slot & 15;

    const int tid   = threadIdx.x;
    const int gid   = tid >> 8;
    const int wtid  = tid & 255;
    const int wave4 = wtid >> 6;
    const int lane  = tid & 63;
    const int Qq    = lane & 15;
    const int G     = lane >> 4;

    char* gbase = sAll + gid * 65536;

    const int krow[4] = { (0*256 + wtid) >> 4, (1*256 + wtid) >> 4,
                          (2*256 + wtid) >> 4, (3*256 + wtid) >> 4 };
    const int kc8 = wtid & 15;
    const int vd  = lane * 2;
    const int vkvb[2] = { wave4, 4 + wave4 };

    const float scale2 = 0.08838834764831845f * 1.4426950408889634f;
    const float THR2   = 11.541560327111707f;

    u32x4 kreg[4];
    unsigned vreg[2][8];

    #pragma unroll
    for (int phase = 0; phase < 2; ++phase) {
        const int jt  = phase ? (31 - pairb) : pairb;
        const int q0w = jt * 64 + wave4 * 16;

        V8 qf[4];
        #pragma unroll
        for (int kk = 0; kk < 4; ++kk)
            qf[kk].u = *(const u32x4*)(Q + (size_t)(q0w + Qq) * DIM + h * HD + kk * 32 + G * 8);

        f32x4 o[8] = {};
        float mrow = -1e30f, lrow = 0.f;

        const int n_g = (jt >= gid) ? ((jt - gid) >> 1) + 1 : 0;
        const int nA  = (jt >> 1) + 1;

        if (n_g > 0) {
            STAGE_LOAD(gid * 64);
            STAGE_WRITE(gbase, gbase + 32768);
        }

        int cur = 0;
        for (int s = 0; s < nA; ++s) {
            __syncthreads();

            const bool pf = (s + 1 < n_g);
            if (pf) STAGE_LOAD((2 * (s + 1) + gid) * 64);

            if (s < n_g) {
                const int tcur = 2 * s + gid;
                const int kv0  = tcur * 64;
                char* sKb = gbase + cur * 16384;
                char* sVb = gbase + 32768 + cur * 16384;

                f32x4 sacc[4] = {};
                __builtin_amdgcn_s_setprio(1);
                #pragma unroll
                for (int kk = 0; kk < 4; ++kk) {
                    #pragma unroll
                    for (int cb = 0; cb < 4; ++cb) {
                        int row = cb * 16 + Qq;
                        V8 kf;
                        kf.u = *(const u32x4*)(sKb + ((row * 256 + kk * 64 + G * 16) ^ ((row & 7) << 4)));
                        sacc[cb] = __builtin_amdgcn_mfma_f32_16x16x32_bf16(kf.b, qf[kk].b, sacc[cb], 0, 0, 0);
                    }
                }
                __builtin_amdgcn_s_setprio(0);

                float p[4][4];
                float tmax = -3e38f;
                const int qg = q0w + Qq;
                #pragma unroll
                for (int cb = 0; cb < 4; ++cb)
                    #pragma unroll
                    for (int r = 0; r < 4; ++r) {
                        float s2 = sacc[cb][r] * scale2;
                        if (tcur == jt) {
                            int kvg = kv0 + cb * 16 + G * 4 + r;
                            if (kvg > qg) s2 = -1e30f;
                        }
                        p[cb][r] = s2;
                        tmax = fmaxf(tmax, s2);
                    }
                tmax = fmaxf(tmax, __shfl_xor(tmax, 16));
                tmax = fmaxf(tmax, __shfl_xor(tmax, 32));

                const bool skip = __all(tmax - mrow <= THR2);
                float corr = 1.0f;
                if (!skip) {
                    const float mnew = fmaxf(mrow, tmax);
                    corr = exp2f(mrow - mnew);
                    mrow = mnew;
                }
                float rs = 0.f;
                #pragma unroll
                for (int cb = 0; cb < 4; ++cb)
                    #pragma unroll
                    for (int r = 0; r < 4; ++r) {
                        float e = exp2f(p[cb][r] - mrow);
                        p[cb][r] = e;
                        rs += e;
                    }
                rs += __shfl_xor(rs, 16);
                rs += __shfl_xor(rs, 32);
                lrow = lrow * corr + rs;

                unsigned pk[4][2];
                #pragma unroll
                for (int cb = 0; cb < 4; ++cb) {
                    pk[cb][0] = (unsigned)f2b(p[cb][0]) | ((unsigned)f2b(p[cb][1]) << 16);
                    pk[cb][1] = (unsigned)f2b(p[cb][2]) | ((unsigned)f2b(p[cb][3]) << 16);
                }

                if (!skip) {
                    float cf[4];
                    #pragma unroll
                    for (int r = 0; r < 4; ++r)
                        cf[r] = __shfl(corr, G * 4 + r);
                    #pragma unroll
                    for (int nb = 0; nb < 8; ++nb)
                        #pragma unroll
                        for (int r = 0; r < 4; ++r)
                            o[nb][r] *= cf[r];
                }

                const int sLo = ((G & 1) * 2) * 16 + Qq;
                const int sHi = sLo + 16;
                const bool hiC = (G >> 1);
                #pragma unroll
                for (int kk2 = 0; kk2 < 2; ++kk2) {
                    const int c0 = kk2 * 2, c1 = c0 + 1;
                    unsigned w0a = __shfl(pk[c0][0], sLo), w0b = __shfl(pk[c1][0], sLo);
                    unsigned w1a = __shfl(pk[c0][1], sLo), w1b = __shfl(pk[c1][1], sLo);
                    unsigned w2a = __shfl(pk[c0][0], sHi), w2b = __shfl(pk[c1][0], sHi);
                    unsigned w3a = __shfl(pk[c0][1], sHi), w3b = __shfl(pk[c1][1], sHi);
                    V8 pa;
                    pa.u[0] = hiC ? w0b : w0a;
                    pa.u[1] = hiC ? w1b : w1a;
                    pa.u[2] = hiC ? w2b : w2a;
                    pa.u[3] = hiC ? w3b : w3a;
                    __builtin_amdgcn_s_setprio(1);
                    #pragma unroll
                    for (int nb = 0; nb < 8; ++nb) {
                        int d = nb * 16 + Qq;
                        V8 vf;
                        vf.u = *(const u32x4*)(sVb + ((d * 128 + kk2 * 64 + G * 16) ^ ((d & 7) << 4)));
                        o[nb] = __builtin_amdgcn_mfma_f32_16x16x32_bf16(pa.b, vf.b, o[nb], 0, 0, 0);
                    }
                    __builtin_amdgcn_s_setprio(0);
                }
            }

            if (pf) STAGE_WRITE(gbase + (cur ^ 1) * 16384, gbase + 32768 + (cur ^ 1) * 16384);
            cur ^= 1;
        }

        __syncthreads();
        float* mrg = (float*)sAll;
        float* mlb = (float*)(sAll + 33792);
        if (gid == 1) {
            #pragma unroll
            for (int nb = 0; nb < 8; ++nb)
                #pragma unroll
                for (int r = 0; r < 4; ++r) {
                    int qloc = wave4 * 16 + G * 4 + r;
                    mrg[qloc * 132 + nb * 16 + Qq] = o[nb][r];
                }
            if (G == 0) {
                int qloc = wave4 * 16 + Qq;
                mlb[qloc]      = mrow;
                mlb[64 + qloc] = lrow;
            }
        }
        __syncthreads();
        if (gid == 0) {
            int qloc0 = wave4 * 16 + Qq;
            float mB = mlb[qloc0], lB = mlb[64 + qloc0];
            float m  = fmaxf(mrow, mB);
            float cA = exp2f(mrow - m), cB = exp2f(mB - m);
            float linv = 1.f / (lrow * cA + lB * cB);
            float cAr[4], cBr[4], lir[4];
            #pragma unroll
            for (int r = 0; r < 4; ++r) {
                cAr[r] = __shfl(cA, G * 4 + r);
                cBr[r] = __shfl(cB, G * 4 + r);
                lir[r] = __shfl(linv, G * 4 + r);
            }
            #pragma unroll
            for (int nb = 0; nb < 8; ++nb)
                #pragma unroll
                for (int r = 0; r < 4; ++r) {
                    int qloc = wave4 * 16 + G * 4 + r;
                    float ob  = mrg[qloc * 132 + nb * 16 + Qq];
                    float val = (o[nb][r] * cAr[r] + ob * cBr[r]) * lir[r];
                    int qgr = jt * 64 + qloc;
                    O[(size_t)qgr * DIM + h * HD + nb * 16 + Qq] = f2b(val);
                }
        }
        __syncthreads();
    }
}

// ---------------------------------------------------------------------------
extern "C" void kernel_launch(void* const* d_in, const int* in_sizes, int n_in,
                              void* d_out, int out_size, void* d_ws, size_t ws_size,
                              hipStream_t stream)
{
    const float* x    = (const float*)d_in[0];
    const float* wq   = (const float*)d_in[1];
    const float* wkvd = (const float*)d_in[2];
    const float* wkvu = (const float*)d_in[3];
    const float* wo   = (const float*)d_in[4];
    const float* qnw  = (const float*)d_in[5];
    const float* knw  = (const float*)d_in[6];
    const float* fc   = (const float*)d_in[7];
    const float* fs   = (const float*)d_in[8];
    float* out = (float*)d_out;

    char* ws = (char*)d_ws;
    const size_t MB = 1024 * 1024;
    ushort_t* xb    = (ushort_t*)(ws);
    ushort_t* att   = (ushort_t*)(ws);            // alias: xb dead after QKV gemm
    ushort_t* Qb    = (ushort_t*)(ws + 8  * MB);
    ushort_t* wqb   = (ushort_t*)(ws + 16 * MB);
    ushort_t* wkvdb = (ushort_t*)(ws + 24 * MB);
    ushort_t* kvb   = (ushort_t*)(ws + 16 * MB);  // alias: weights dead after QKV gemm
    ushort_t* lat   = (ushort_t*)(ws + 32 * MB);
    ushort_t* wkvub = (ushort_t*)(ws + 34 * MB);
    ushort_t* wob   = (ushort_t*)(ws + 38 * MB);

    cvtk<<<dim3(2048), dim3(256), 0, stream>>>(x, wq, wkvd, wkvu, wo,
                                               xb, wqb, wkvdb, wkvub, wob);
    // gemm1: 64x128 tile, 640 blocks; Q cols get fused rmsnorm+rope; lat plain.
    gemm_nt<64, 128, false, true><<<dim3(32, 20), dim3(256), 0, stream>>>(
        xb, wqb, Qb, 2048, 2048, wkvdb, lat, 2048, 512, qnw, fc, fs);
    // gemm2: 128x128, 512 blocks.
    gemm_nt<128, 128, false, false><<<dim3(16, 32), dim3(256), 0, stream>>>(
        lat, wkvub, kvb, 2048, 512, nullptr, nullptr, 4096, 0, nullptr, nullptr, nullptr);
    // K-norm only (Q already normed in gemm1 epilogue).
    norm_ropeK<<<dim3(2048), dim3(256), 0, stream>>>(kvb, knw, fc, fs);
    attn_kernel<<<dim3(256), dim3(512), 0, stream>>>(Qb, kvb, att);
    // gemm4: 128x64 tile, 512 blocks, f32 out.
    gemm_nt<128, 64, true, false><<<dim3(16, 32), dim3(256), 0, stream>>>(
        att, wob, out, 2048, 2048, nullptr, nullptr, 2048, 0, nullptr, nullptr, nullptr);
}